// Round 7
// baseline (883.732 us; speedup 1.0000x reference)
//
#include <hip/hip_runtime.h>

// MyRNN: B=128, T=80, E=100, V=10000, U=512
// 8 clusters x 32 member-blocks formed dynamically by physical XCD
// (s_getreg HW_REG_XCC_ID + atomic slot grab): with ~131KB LDS -> 1 block/CU,
// grid 256 fills all CUs => each XCD hosts exactly 32 blocks => a cluster's
// members share one L2 BY CONSTRUCTION. Cluster c owns batch rows
// [16c,16c+16); member m owns cols [16m,16m+16) of rk0/rk1/k1 (LDS, hi/lo).
// History: R7 745us (data via XCD L2, MALL atomic ctr) -> R9 588us (parallel
// per-member MALL flags) -> R12 572us (sE overlap, w0 poll, 128B flag lines).
// HW facts: no prompt store-side L2 signaling (R8/R10); global atomics are
// memory-side, write to HBM (R11). MALL RT ~1us is the signaling floor.
// R13 (652us) post-mortem: wave-autonomous 8-row dual streams DOUBLED MFMA
// (row dup) without shortening the per-stream chain -> regression.
// R14: chunk-granular streaming consumption, h never touches LDS.
//   MFMA A-frag (16x16x32) = lane l reads h[l&15][32p+8*(l>>4)+j] = 8
//   consecutive packed u32 = 2 dwordx4 -> consume hPk/h0Pk DIRECTLY from L2
//   into MFMA operands (unpack hi/lo in regs). Per member-pair chunk:
//   poll pair flags -> 2 sc0 loads -> 4 MFMA, software-pipelined (counted
//   vmcnt(2) + sched_barrier, rule 18). Waiting for member p overlaps MFMA
//   of members < p: straggler skew AND the old bulk-gather+MFMA tail are
//   absorbed into the arrival window. Pairs staggered by member id (spread
//   flag/chunk hotspots). One intra-block __syncthreads per round A
//   (certifies both waves consumed h(t-1) before the h0 post). WAR safety:
//   h0(t+1) writes happen after polling all flags>=2t+2 (=> all wave1s done
//   with h0(t)); h(t) writes happen after polling all >=2t+1 (=> all passed
//   the round-A barrier => consumed h(t-1)). Flags monotonic 1..160.

typedef __attribute__((ext_vector_type(8))) short short8;
typedef __attribute__((ext_vector_type(4))) float f32x4;
typedef __attribute__((ext_vector_type(4))) unsigned uint4v;

#define MFMA16(a,b,c) __builtin_amdgcn_mfma_f32_16x16x32_bf16(a,b,c,0,0,0)
#define LOAD_RLX(p)    __hip_atomic_load((p), __ATOMIC_RELAXED, __HIP_MEMORY_SCOPE_AGENT)
#define STORE_RLX(p,v) __hip_atomic_store((p), (v), __ATOMIC_RELAXED, __HIP_MEMORY_SCOPE_AGENT)
#define ADD_RLX(p,v)   __hip_atomic_fetch_add((p), (v), __ATOMIC_RELAXED, __HIP_MEMORY_SCOPE_AGENT)
#define GLOAD4(dst, addr) asm volatile("global_load_dwordx4 %0, %1, off sc0" : "=v"(dst) : "v"(addr))

__device__ __forceinline__ short f2bf(float v){
  unsigned u = __float_as_uint(v);
  u = (u + 0x7fffu + ((u >> 16) & 1u)) >> 16;   // RNE to bf16
  return (short)u;
}
__device__ __forceinline__ float bf2f(short s){
  return __uint_as_float(((unsigned)(unsigned short)s) << 16);
}
__device__ __forceinline__ float fast_tanh(float x){
  x = fminf(15.f, fmaxf(-15.f, x));
  float e = __expf(2.f * x);
  return (e - 1.f) * __builtin_amdgcn_rcpf(e + 1.f);
}

__launch_bounds__(128, 1)
__global__ void rnn_kernel(const int* __restrict__ tokens,
                           const float* __restrict__ emb,
                           const float* __restrict__ k0,
                           const float* __restrict__ rk0,
                           const float* __restrict__ b0,
                           const float* __restrict__ k1,
                           const float* __restrict__ rk1,
                           const float* __restrict__ b1,
                           const float* __restrict__ wd,
                           const float* __restrict__ bd,
                           float* __restrict__ out,
                           char* __restrict__ ws)
{
  constexpr int T = 80, E = 100, U = 512;
  const int tid  = threadIdx.x;
  const int w    = tid >> 6;          // wave id (0/1)
  const int lane = tid & 63;
  const int m    = lane & 15;         // A-row / B,C col
  const int q    = lane >> 4;         // quad 0..3

  __shared__ __align__(16) short sW[6][16][520];     // rk0 hi/lo, rk1 hi/lo, k1 hi/lo : [col][k]
  __shared__ __align__(16) short sE[2][2][16][136];  // emb rows hi,lo, DOUBLE-BUFFERED by t&1
  __shared__ __align__(16) short sK0[2][16][136];    // k0 slice hi,lo : [col][k] (padded)
  __shared__ int   sTok[16][80];
  __shared__ float sB0[16], sB1[16];
  __shared__ int   sReg[2];

  int*      regCnt = (int*)(ws + 512);             // 8 registration counters (MALL)
  int*      flags  = (int*)(ws + 4096);            // 256 member flags, 128B stride (MALL)
  unsigned* hPk    = (unsigned*)(ws + 40960);      // h  packed (hi<<16|lo), [128][512]
  unsigned* h0Pk   = hPk + 128*U;                  // h0 packed

  // -------- dynamic cluster formation: cluster id = physical XCD --------
  int xcc;
  asm volatile("s_getreg_b32 %0, hwreg(HW_REG_XCC_ID)" : "=s"(xcc));
  if (tid == 0){
    int slot = ADD_RLX(regCnt + (xcc & 7)*16, 1);  // 0..31 within this XCD
    sReg[0] = xcc & 7;
    sReg[1] = slot;
  }
  __syncthreads();
  const int cl  = sReg[0];
  const int mem = sReg[1];
  int* const myFlag = flags + (cl*32 + mem)*32;

  // ---------------- prologue: stationary weights -> LDS ----------------
  const float* mats[3] = { rk0, rk1, k1 };
  for (int mi = 0; mi < 3; ++mi){
    const float* G = mats[mi];
    for (int i = tid; i < 16*U; i += 128){
      int k = i >> 4, c = i & 15;
      float v  = G[k*U + mem*16 + c];
      short hi = f2bf(v);
      short lo = f2bf(v - bf2f(hi));
      sW[2*mi+0][c][k] = hi;
      sW[2*mi+1][c][k] = lo;
    }
  }
  for (int i = tid; i < 2*2*16*136; i += 128) ((short*)sE)[i]  = 0;
  for (int i = tid; i < 2*16*136;   i += 128) ((short*)sK0)[i] = 0;
  __syncthreads();
  for (int i = tid; i < 16*E; i += 128){
    int e = i >> 4, c = i & 15;
    float v  = k0[e*U + mem*16 + c];
    short hi = f2bf(v);
    short lo = f2bf(v - bf2f(hi));
    sK0[0][c][e] = hi; sK0[1][c][e] = lo;
  }
  for (int i = tid; i < 16*T; i += 128){
    int r = i / T, t = i - r*T;
    sTok[r][t] = tokens[(cl*16 + r)*T + t];
  }
  if (tid < 16){ sB0[tid] = b0[mem*16 + tid]; sB1[tid] = b1[mem*16 + tid]; }
  __syncthreads();
  // stage sE buf0 for t=0 (needs sTok)
  for (int i = tid; i < 16*E; i += 128){
    int row = i / E, e = i - row*E;
    float v  = emb[sTok[row][0]*E + e];
    short hi = f2bf(v);
    short lo = f2bf(v - bf2f(hi));
    sE[0][0][row][e] = hi; sE[0][1][row][e] = lo;
  }
  __syncthreads();

  // poll one member PAIR's flags (lane&1 selects pair half); 'skip' member
  // is certified by other means (barrier / own program order).
  auto pollPair = [&](int pp, int target, int skip){
    const int who = 2*pp + (lane & 1);
    int* a = flags + (cl*32 + who)*32;
    const bool act = (who != skip);
    for (;;){
      int v = target;
      if (act) v = LOAD_RLX(a);
      if (!__any(v < target)) return;
    }
  };

  // stream 16 member-pair chunks of src (packed u32 [row][k]) through
  // MFMA with sW[wsH]/sW[wsL], accumulating into Za..Zd. Direct-to-register:
  // lane l loads src[(cl*16 + (l&15))*U + 32*pp + 8*(l>>4) + 0..7] = 2 dwordx4.
  auto stream16 = [&](const unsigned* src, int target, int wsH, int wsL, int skip,
                      f32x4& Za, f32x4& Zb, f32x4& Zc, f32x4& Zd){
    const unsigned* pa = src + (cl*16 + m)*U + q*8;
    const int pstart = mem >> 1;
    uint4 c0, c1, n0, n1;
    {
      int pp0 = pstart;
      pollPair(pp0, target, skip);
      GLOAD4(c0, pa + 32*pp0);
      GLOAD4(c1, pa + 32*pp0 + 4);
    }
    #pragma unroll
    for (int p = 0; p < 16; ++p){
      const int pp = (p + pstart) & 15;
      if (p < 15){
        const int ppn = (p + 1 + pstart) & 15;
        pollPair(ppn, target, skip);           // its value-use drains vmcnt
        GLOAD4(n0, pa + 32*ppn);
        GLOAD4(n1, pa + 32*ppn + 4);
        asm volatile("s_waitcnt vmcnt(2)" ::: "memory");  // c0,c1 ready
      } else {
        asm volatile("s_waitcnt vmcnt(0)" ::: "memory");
      }
      __builtin_amdgcn_sched_barrier(0);       // rule 18: pin unpack/MFMA after wait
      uint4v hh, ll;
      hh.x = (c0.x >> 16)     | (c0.y & 0xffff0000u);
      hh.y = (c0.z >> 16)     | (c0.w & 0xffff0000u);
      hh.z = (c1.x >> 16)     | (c1.y & 0xffff0000u);
      hh.w = (c1.z >> 16)     | (c1.w & 0xffff0000u);
      ll.x = (c0.x & 0xffffu) | (c0.y << 16);
      ll.y = (c0.z & 0xffffu) | (c0.w << 16);
      ll.z = (c1.x & 0xffffu) | (c1.y << 16);
      ll.w = (c1.z & 0xffffu) | (c1.w << 16);
      short8 ah = __builtin_bit_cast(short8, hh);
      short8 al = __builtin_bit_cast(short8, ll);
      short8 bh = *(const short8*)&sW[wsH][m][pp*32 + q*8];
      short8 bl = *(const short8*)&sW[wsL][m][pp*32 + q*8];
      Za = MFMA16(ah, bh, Za); Zb = MFMA16(al, bh, Zb);
      Zc = MFMA16(ah, bl, Zc); Zd = MFMA16(al, bl, Zd);
      if (p < 15){ c0 = n0; c1 = n1; }
    }
  };

  const f32x4 zero4 = {0.f, 0.f, 0.f, 0.f};

  // ---------------- recurrence ----------------
  for (int t = 0; t < T; ++t){
    f32x4 za = zero4, zb = zero4, zc = zero4, zd = zero4;

    // ---- round A: w0: h0 = tanh(x@k0 + h@rk0 + b0); w1: z1 = h@rk1
    if (w == 0){
      #pragma unroll
      for (int kk = 0; kk < 4; ++kk){          // x@k0 fills the arrival window
        short8 ah = *(const short8*)&sE[t&1][0][m][kk*32 + q*8];
        short8 al = *(const short8*)&sE[t&1][1][m][kk*32 + q*8];
        short8 bh = *(const short8*)&sK0[0][m][kk*32 + q*8];
        short8 bl = *(const short8*)&sK0[1][m][kk*32 + q*8];
        za = MFMA16(ah, bh, za); zb = MFMA16(al, bh, zb);
        zc = MFMA16(ah, bl, zc); zd = MFMA16(al, bl, zd);
      }
      if (t > 0) stream16(hPk, 2*t, 0, 1, -1, za, zb, zc, zd);
      f32x4 z = za; z += zb; z += zc; z += zd;
      #pragma unroll
      for (int r = 0; r < 4; ++r){
        float h0v = fast_tanh(z[r] + sB0[m]);
        short hi = f2bf(h0v);
        short lo = f2bf(h0v - bf2f(hi));
        unsigned pk = ((unsigned)(unsigned short)hi << 16) | (unsigned short)lo;
        h0Pk[(cl*16 + q*4 + r)*U + mem*16 + m] = pk;   // plain store -> XCD L2
      }
      asm volatile("s_waitcnt vmcnt(0)" ::: "memory");
    } else {
      if (t > 0) stream16(hPk, 2*t, 2, 3, mem, za, zb, zc, zd);  // z1; own flag
    }                                                            // by program order
    __syncthreads();   // both waves consumed h(t-1); w0's h0 drained to L2
    if (w == 0 && lane == 0) STORE_RLX(myFlag, 2*t + 1);

    // ---- round B: w1: h = tanh(h0@k1 + z1 + b1); w0: stage sE[t+1]
    if (w == 1){
      stream16(h0Pk, 2*t + 1, 4, 5, mem, za, zb, zc, zd);  // own h0 certified
      f32x4 y = za; y += zb; y += zc; y += zd;             // by the barrier
      #pragma unroll
      for (int r = 0; r < 4; ++r){
        float h1v = fast_tanh(y[r] + sB1[m]);
        short hi = f2bf(h1v);
        short lo = f2bf(h1v - bf2f(hi));
        unsigned pk = ((unsigned)(unsigned short)hi << 16) | (unsigned short)lo;
        hPk[(cl*16 + q*4 + r)*U + mem*16 + m] = pk;        // plain store -> XCD L2
      }
      asm volatile("s_waitcnt vmcnt(0)" ::: "memory");
      if (lane == 0) STORE_RLX(myFlag, 2*t + 2);
    } else if (t + 1 < T){
      float ev[25];
      #pragma unroll
      for (int p2 = 0; p2 < 25; ++p2){
        int i = lane + p2*64;                  // 25*64 = 1600 = 16*E exactly
        ev[p2] = emb[sTok[i/100][t+1]*E + (i % 100)];
      }
      #pragma unroll
      for (int p2 = 0; p2 < 25; ++p2){
        int i = lane + p2*64;
        int row = i / 100, e = i % 100;
        short hi = f2bf(ev[p2]);
        short lo = f2bf(ev[p2] - bf2f(hi));
        sE[(t+1)&1][0][row][e] = hi; sE[(t+1)&1][1][row][e] = lo;
      }
    }
    // no trailing barrier: w0's next x@k0 reads sE it staged itself; its next
    // h-stream polls >=2t+2 (which certifies all wave1s done with h0(t)).
  }

  // ---------------- epilogue: logits = h@wd + bd ; sigmoid ----------------
  if (mem == 0){
    { int* a = flags + (cl*32 + (lane & 31))*32;
      while (__any(LOAD_RLX(a) < 2*T)) {} }
    int row = w*8 + (lane >> 3), seg = lane & 7;
    const unsigned* hp = hPk + (cl*16 + row)*U + seg*64;
    float acc = 0.f;
    #pragma unroll
    for (int b = 0; b < 4; ++b){
      uint4 r0, r1, r2, r3;
      const unsigned* pb = hp + b*16;
      GLOAD4(r0, pb); GLOAD4(r1, pb + 4); GLOAD4(r2, pb + 8); GLOAD4(r3, pb + 12);
      asm volatile("s_waitcnt vmcnt(0)" ::: "memory");
      const float* wb = wd + seg*64 + b*16;
      uint4 rs[4] = { r0, r1, r2, r3 };
      #pragma unroll
      for (int v4 = 0; v4 < 4; ++v4){
        acc += (bf2f((short)(rs[v4].x >> 16)) + bf2f((short)(rs[v4].x & 0xffff))) * wb[v4*4 + 0];
        acc += (bf2f((short)(rs[v4].y >> 16)) + bf2f((short)(rs[v4].y & 0xffff))) * wb[v4*4 + 1];
        acc += (bf2f((short)(rs[v4].z >> 16)) + bf2f((short)(rs[v4].z & 0xffff))) * wb[v4*4 + 2];
        acc += (bf2f((short)(rs[v4].w >> 16)) + bf2f((short)(rs[v4].w & 0xffff))) * wb[v4*4 + 3];
      }
    }
    acc += __shfl_xor(acc, 1);
    acc += __shfl_xor(acc, 2);
    acc += __shfl_xor(acc, 4);
    if (seg == 0) out[cl*16 + row] = 1.f / (1.f + __expf(-(acc + bd[0])));
  }

  // replay hygiene: flush this XCD's dirty L2 exchange lines (one-time cost)
  __threadfence();
}

extern "C" void kernel_launch(void* const* d_in, const int* in_sizes, int n_in,
                              void* d_out, int out_size, void* d_ws, size_t ws_size,
                              hipStream_t stream) {
  const int*   tokens = (const int*)  d_in[0];
  const float* emb    = (const float*)d_in[1];
  const float* k0     = (const float*)d_in[2];
  const float* rk0    = (const float*)d_in[3];
  const float* b0     = (const float*)d_in[4];
  const float* k1     = (const float*)d_in[5];
  const float* rk1    = (const float*)d_in[6];
  const float* b1     = (const float*)d_in[7];
  const float* wd     = (const float*)d_in[8];
  const float* bd     = (const float*)d_in[9];

  // Zero registration counters + flag region (0xAA poison breaks monotonic
  // arith). regCnt@512, flags@4096..36864; exchange data starts at 40960
  // (fully rewritten before first consumption — no memset needed there).
  hipMemsetAsync(d_ws, 0, 40960, stream);

  hipLaunchKernelGGL(rnn_kernel, dim3(256), dim3(128), 0, stream,
                     tokens, emb, k0, rk0, b0, k1, rk1, b1, wd, bd,
                     (float*)d_out, (char*)d_ws);
}

// Round 8
// 815.126 us; speedup vs baseline: 1.0842x; 1.0842x over previous
//
#include <hip/hip_runtime.h>

// MyRNN: B=128, T=80, E=100, V=10000, U=512
// 8 clusters x 32 member-blocks, formed DYNAMICALLY by physical XCD
// (s_getreg HW_REG_XCC_ID + atomic slot grab): with 156KB LDS -> 1 block/CU,
// grid 256 fills all CUs, so each XCD hosts exactly 32 blocks -> a cluster's
// members share one L2 BY CONSTRUCTION. Cluster c owns batch rows
// [16c,16c+16); member m owns cols [16m,16m+16) of rk0/rk1/k1 (LDS, hi/lo).
// R1-R6: MALL data-path protocol variants pinned at 5.5-7us/exchange.
// R7 (745us): data via plain stores + sc0 dwordx4 gathers; MALL atomic ctr.
// R9 (588us): per-member MALL flags -> parallel posts, wave-parallel poll.
// R8/R10: plain-store flags not promptly pollable (store-side lag). HW fact.
// R11 (1445us): global atomics are MEMORY-SIDE, write through to HBM. HW fact.
// R12 (572us): R9 + sE-overlap-by-w1 + w0-only-poll + 128B flag stride.
// R13 (652us): wave-autonomous dual streams -> 2x MFMA (row dup), no chain
//   shortening. R14 (826us): chunk-granular streaming -> 16 SEQUENTIAL MALL
//   RTs per exchange (each poll load is a full RT even when satisfied).
//   Lesson: poll all 32 flags in ONE wave-parallel shot; never serialize
//   protocol loads.
// R15 post-mortem of R12's FETCH_SIZE=20.4GB @ 36GB/s: ~18GB is SPIN traffic
//   reaching HBM -> ws is effectively UNCACHED at the MALL for agent-scope
//   accesses (consistent with R2-R6/R8/R10/R11). Flag "line isolation"
//   (128B stride) made every poll iteration 32 scattered HBM bursts; under a
//   memory-side cache there is no ownership to avoid -- isolation bought
//   nothing and multiplied contention. R15 = R12 verbatim + ONE change:
//   each cluster's 32 flags packed into ONE 128B line (4B stride). A poll
//   touches 1-2 HBM bursts instead of 32; queueing collapses. Posts to a
//   shared line are safe memory-side (no invalidation, writes just queue).

typedef __attribute__((ext_vector_type(8))) short short8;
typedef __attribute__((ext_vector_type(4))) float f32x4;

#define MFMA16(a,b,c) __builtin_amdgcn_mfma_f32_16x16x32_bf16(a,b,c,0,0,0)
#define LOAD_RLX(p)    __hip_atomic_load((p), __ATOMIC_RELAXED, __HIP_MEMORY_SCOPE_AGENT)
#define STORE_RLX(p,v) __hip_atomic_store((p), (v), __ATOMIC_RELAXED, __HIP_MEMORY_SCOPE_AGENT)
#define ADD_RLX(p,v)   __hip_atomic_fetch_add((p), (v), __ATOMIC_RELAXED, __HIP_MEMORY_SCOPE_AGENT)

__device__ __forceinline__ short f2bf(float v){
  unsigned u = __float_as_uint(v);
  u = (u + 0x7fffu + ((u >> 16) & 1u)) >> 16;   // RNE to bf16
  return (short)u;
}
__device__ __forceinline__ float bf2f(short s){
  return __uint_as_float(((unsigned)(unsigned short)s) << 16);
}
__device__ __forceinline__ float fast_tanh(float x){
  x = fminf(15.f, fmaxf(-15.f, x));
  float e = __expf(2.f * x);
  return (e - 1.f) * __builtin_amdgcn_rcpf(e + 1.f);
}

__launch_bounds__(128, 1)
__global__ void rnn_kernel(const int* __restrict__ tokens,
                           const float* __restrict__ emb,
                           const float* __restrict__ k0,
                           const float* __restrict__ rk0,
                           const float* __restrict__ b0,
                           const float* __restrict__ k1,
                           const float* __restrict__ rk1,
                           const float* __restrict__ b1,
                           const float* __restrict__ wd,
                           const float* __restrict__ bd,
                           float* __restrict__ out,
                           char* __restrict__ ws)
{
  constexpr int T = 80, E = 100, U = 512;
  const int tid  = threadIdx.x;
  const int w    = tid >> 6;          // wave id (0/1)
  const int lane = tid & 63;
  const int m    = lane & 15;         // row (A) / col (B,C)
  const int q    = lane >> 4;         // quad 0..3

  __shared__ __align__(16) short sW[6][16][520];   // rk0 hi/lo, rk1 hi/lo, k1 hi/lo : [col][k]
  __shared__ __align__(16) short sH[2][16][520];   // h / h0 staging hi,lo : [row][k]
  __shared__ __align__(16) short sE[2][16][136];   // emb rows hi,lo (K padded to 128 w/ zeros)
  __shared__ __align__(16) short sK0[2][16][136];  // k0 slice hi,lo : [col][k] (padded)
  __shared__ int   sTok[16][80];
  __shared__ float sB0[16], sB1[16];
  __shared__ float sRed[16][8];
  __shared__ int   sReg[2];

  // ws layout: regCnt@512 (MALL), flags@4096: cluster c's 32 member flags
  // COMPACT in one 128B line (4B stride) -> a wave-parallel poll touches
  // 1-2 HBM bursts instead of 32. Exchange data @ 40960.
  int*      regCnt = (int*)(ws + 512);             // 8 registration counters, 64B stride
  int*      flags  = (int*)(ws + 4096);            // [cl][mem] round-id flags, COMPACT
  unsigned* hPk    = (unsigned*)(ws + 40960);      // h1 packed (hi<<16|lo), [128][512]
  unsigned* h0Pk   = hPk + 128*U;                  // h0 packed

  // -------- dynamic cluster formation: cluster id = physical XCD --------
  int xcc;
  asm volatile("s_getreg_b32 %0, hwreg(HW_REG_XCC_ID)" : "=s"(xcc));
  if (tid == 0){
    int slot = ADD_RLX(regCnt + (xcc & 7)*16, 1);  // 0..31 within this XCD
    sReg[0] = xcc & 7;
    sReg[1] = slot;
  }
  __syncthreads();
  const int cl  = sReg[0];
  const int mem = sReg[1];
  int* const myFlag   = flags + cl*32 + mem;          // 4B stride, one line/cluster
  int* const pollAddr = flags + cl*32 + (lane & 31);  // lane -> member flag

  // ---------------- prologue: stationary weights -> LDS ----------------
  const float* mats[3] = { rk0, rk1, k1 };
  for (int mi = 0; mi < 3; ++mi){
    const float* G = mats[mi];
    for (int i = tid; i < 16*U; i += 128){
      int k = i >> 4, c = i & 15;
      float v  = G[k*U + mem*16 + c];
      short hi = f2bf(v);
      short lo = f2bf(v - bf2f(hi));
      sW[2*mi+0][c][k] = hi;
      sW[2*mi+1][c][k] = lo;
    }
  }
  for (int i = tid; i < 2*16*136; i += 128){ ((short*)sE)[i] = 0; ((short*)sK0)[i] = 0; }
  __syncthreads();
  for (int i = tid; i < 16*E; i += 128){
    int e = i >> 4, c = i & 15;
    float v  = k0[e*U + mem*16 + c];
    short hi = f2bf(v);
    short lo = f2bf(v - bf2f(hi));
    sK0[0][c][e] = hi; sK0[1][c][e] = lo;
  }
  for (int i = tid; i < 16*T; i += 128){
    int r = i / T, t = i - r*T;
    sTok[r][t] = tokens[(cl*16 + r)*T + t];
  }
  if (tid < 16){ sB0[tid] = b0[mem*16 + tid]; sB1[tid] = b1[mem*16 + tid]; }
  __syncthreads();

  // post: drain data stores (vmcnt ack), then lane0 agent-stores the round
  // id to this member's flag word (R9-proven path; compact line).
  auto post = [&](int val){
    asm volatile("s_waitcnt vmcnt(0)" ::: "memory");
    if (lane == 0) STORE_RLX(myFlag, val);
  };
  // wave-parallel poll (WAVE0 ONLY; following barrier releases w1): one
  // iteration = 32 lane loads from ONE 128B line = 1-2 HBM bursts.
  auto pollFlags = [&](int target){
    while (__any(LOAD_RLX(pollAddr) < target)) {}
  };
  // gather: 16x dwordx4 sc0, then unpack into sH hi/lo.
  auto gather = [&](const unsigned* srcPk){
    const uint4* s = (const uint4*)(srcPk + cl*16*U);   // 2048 uint4 = 32 KB
    uint4 r[16];
    #pragma unroll
    for (int j = 0; j < 16; ++j)
      asm volatile("global_load_dwordx4 %0, %1, off sc0"
                   : "=v"(r[j]) : "v"(&s[j*128 + tid]));
    asm volatile("s_waitcnt vmcnt(0)" ::: "memory");
    #pragma unroll
    for (int j = 0; j < 16; ++j){
      int i = j*128 + tid, row = i >> 7, c = (i & 127) * 4;
      unsigned h0 = (r[j].x >> 16)     | (r[j].y & 0xffff0000u);
      unsigned h1 = (r[j].z >> 16)     | (r[j].w & 0xffff0000u);
      unsigned l0 = (r[j].x & 0xffffu) | (r[j].y << 16);
      unsigned l1 = (r[j].z & 0xffffu) | (r[j].w << 16);
      uint2 hh; hh.x = h0; hh.y = h1;
      uint2 ll; ll.x = l0; ll.y = l1;
      *(uint2*)&sH[0][row][c] = hh;
      *(uint2*)&sH[1][row][c] = ll;
    }
  };

  const f32x4 zero4 = {0.f, 0.f, 0.f, 0.f};

  // ---------------- recurrence ----------------
  for (int t = 0; t < T; ++t){
    // wave1 stages sE[t] OFF the critical path while wave0 polls.
    // Safe: wave0's last sE[t-1] read retired before the round-B barriers
    // of t-1 (which wave1 passed to get here); wave1 never reads sE.
    if (w == 1){
      float ev[25];
      #pragma unroll
      for (int p = 0; p < 25; ++p){
        int i = lane + p*64;                 // 25*64 = 1600 = 16*E exactly
        ev[p] = emb[sTok[i/E][t]*E + (i % E)];
      }
      #pragma unroll
      for (int p = 0; p < 25; ++p){
        int i = lane + p*64;
        int row = i / E, e = i % E;
        short hi = f2bf(ev[p]);
        short lo = f2bf(ev[p] - bf2f(hi));
        sE[0][row][e] = hi; sE[1][row][e] = lo;
      }
    } else {
      if (t > 0) pollFlags(2*t);             // all round-B(t-1) posts
    }
    __syncthreads();
    if (t > 0) gather(hPk);
    __syncthreads();

    // ---- round A: wave0: h0 = tanh(x@k0 + h@rk0 + b0); wave1: h@rk1 partial
    f32x4 z1a = zero4, z1b = zero4, z1c = zero4, z1d = zero4;
    if (w == 0){
      f32x4 za = zero4, zb = zero4, zc = zero4, zd = zero4;
      #pragma unroll
      for (int kk = 0; kk < 4; ++kk){
        short8 ah = *(const short8*)&sE[0][m][kk*32 + q*8];
        short8 al = *(const short8*)&sE[1][m][kk*32 + q*8];
        short8 bh = *(const short8*)&sK0[0][m][kk*32 + q*8];
        short8 bl = *(const short8*)&sK0[1][m][kk*32 + q*8];
        za = MFMA16(ah, bh, za); zb = MFMA16(al, bh, zb);
        zc = MFMA16(ah, bl, zc); zd = MFMA16(al, bl, zd);
      }
      if (t > 0){
        #pragma unroll
        for (int kk = 0; kk < 16; ++kk){
          short8 ah = *(const short8*)&sH[0][m][kk*32 + q*8];
          short8 al = *(const short8*)&sH[1][m][kk*32 + q*8];
          short8 bh = *(const short8*)&sW[0][m][kk*32 + q*8];
          short8 bl = *(const short8*)&sW[1][m][kk*32 + q*8];
          za = MFMA16(ah, bh, za); zb = MFMA16(al, bh, zb);
          zc = MFMA16(ah, bl, zc); zd = MFMA16(al, bl, zd);
        }
      }
      f32x4 z = za; z += zb; z += zc; z += zd;
      #pragma unroll
      for (int r = 0; r < 4; ++r){
        float h0v = fast_tanh(z[r] + sB0[m]);
        short hi = f2bf(h0v);
        short lo = f2bf(h0v - bf2f(hi));
        int gr = cl*16 + q*4 + r, gc = mem*16 + m;
        unsigned pk = ((unsigned)(unsigned short)hi << 16) | (unsigned short)lo;
        h0Pk[gr*U + gc] = pk;              // plain store (data path)
      }
      post(2*t + 1);                       // h0 ready (this member)
    } else {
      if (t > 0){
        #pragma unroll
        for (int kk = 0; kk < 16; ++kk){
          short8 ah = *(const short8*)&sH[0][m][kk*32 + q*8];
          short8 al = *(const short8*)&sH[1][m][kk*32 + q*8];
          short8 bh = *(const short8*)&sW[2][m][kk*32 + q*8];
          short8 bl = *(const short8*)&sW[3][m][kk*32 + q*8];
          z1a = MFMA16(ah, bh, z1a); z1b = MFMA16(al, bh, z1b);
          z1c = MFMA16(ah, bl, z1c); z1d = MFMA16(al, bl, z1d);
        }
      }
    }

    // ---- round B: h1 = tanh(h0@k1 + h@rk1 + b1)
    if (w == 0) pollFlags(2*t + 1);        // all round-A posts (w1 finishing z1)
    __syncthreads();                       // releases w1; round-A sH reads retired
    gather(h0Pk);
    __syncthreads();
    if (w == 1){
      f32x4 za = zero4, zb = zero4, zc = zero4, zd = zero4;
      #pragma unroll
      for (int kk = 0; kk < 16; ++kk){
        short8 ah = *(const short8*)&sH[0][m][kk*32 + q*8];
        short8 al = *(const short8*)&sH[1][m][kk*32 + q*8];
        short8 bh = *(const short8*)&sW[4][m][kk*32 + q*8];
        short8 bl = *(const short8*)&sW[5][m][kk*32 + q*8];
        za = MFMA16(ah, bh, za); zb = MFMA16(al, bh, zb);
        zc = MFMA16(ah, bl, zc); zd = MFMA16(al, bl, zd);
      }
      f32x4 z = za; z += zb; z += zc; z += zd;
      z += z1a; z += z1b; z += z1c; z += z1d;
      #pragma unroll
      for (int r = 0; r < 4; ++r){
        float h1v = fast_tanh(z[r] + sB1[m]);
        short hi = f2bf(h1v);
        short lo = f2bf(h1v - bf2f(hi));
        int gr = cl*16 + q*4 + r, gc = mem*16 + m;
        unsigned pk = ((unsigned)(unsigned short)hi << 16) | (unsigned short)lo;
        hPk[gr*U + gc] = pk;               // plain store (data path)
      }
      post(2*t + 2);                       // h1 = h(t) ready (this member)
    }
    // no trailing barrier: loop-top poll+barrier aligns waves
  }

  // ---------------- epilogue: logits = h@wd + bd ; sigmoid ----------------
  if (mem == 0){
    if (w == 0) pollFlags(2*T);
    __syncthreads();
    gather(hPk);
    __syncthreads();
    {
      int row = tid >> 3, seg = tid & 7;
      float acc = 0.f;
      for (int u = seg*64; u < seg*64 + 64; ++u){
        float hv = bf2f(sH[0][row][u]) + bf2f(sH[1][row][u]);
        acc += hv * wd[u];
      }
      sRed[row][seg] = acc;
    }
    __syncthreads();
    if (tid < 16){
      float s = bd[0];
      #pragma unroll
      for (int j = 0; j < 8; ++j) s += sRed[tid][j];
      out[cl*16 + tid] = 1.f / (1.f + __expf(-s));
    }
  }

  // replay hygiene (one-time cost)
  __threadfence();
}

extern "C" void kernel_launch(void* const* d_in, const int* in_sizes, int n_in,
                              void* d_out, int out_size, void* d_ws, size_t ws_size,
                              hipStream_t stream) {
  const int*   tokens = (const int*)  d_in[0];
  const float* emb    = (const float*)d_in[1];
  const float* k0     = (const float*)d_in[2];
  const float* rk0    = (const float*)d_in[3];
  const float* b0     = (const float*)d_in[4];
  const float* k1     = (const float*)d_in[5];
  const float* rk1    = (const float*)d_in[6];
  const float* b1     = (const float*)d_in[7];
  const float* wd     = (const float*)d_in[8];
  const float* bd     = (const float*)d_in[9];

  // Zero registration counters + flag region (0xAA poison breaks monotonic
  // arith). regCnt@512, flags@4096..5120; exchange data starts at 40960
  // (fully rewritten at t=0 before first gather — no memset needed there).
  hipMemsetAsync(d_ws, 0, 40960, stream);

  hipLaunchKernelGGL(rnn_kernel, dim3(256), dim3(128), 0, stream,
                     tokens, emb, k0, rk0, b0, k1, rk1, b1, wd, bd,
                     (float*)d_out, (char*)d_ws);
}

// Round 9
// 627.776 us; speedup vs baseline: 1.4077x; 1.2984x over previous
//
#include <hip/hip_runtime.h>

// MyRNN: B=128, T=80, E=100, V=10000, U=512
// 8 clusters x 32 member-blocks, formed DYNAMICALLY by physical XCD
// (s_getreg HW_REG_XCC_ID + atomic slot grab): with 156KB LDS -> 1 block/CU,
// grid 256 fills all CUs, so each XCD hosts exactly 32 blocks -> a cluster's
// members share one L2 BY CONSTRUCTION. Cluster c owns batch rows
// [16c,16c+16); member m owns cols [16m,16m+16) of rk0/rk1/k1 (LDS, hi/lo).
// R1-R6: MALL data-path protocol variants pinned at 5.5-7us/exchange.
// R7 (745us): data via plain stores + sc0 dwordx4 gathers; MALL atomic ctr.
// R9 (588us): per-member MALL flags -> parallel posts, wave-parallel poll.
// R8/R10: plain-store flags not promptly pollable (store-side lag). HW fact.
// R11 (1445us): global atomics execute MEMORY-SIDE, write through to HBM.
//   HW fact -- catastrophic for data, but it means atomic ack == immediate
//   memory-side visibility.
// R12 (572us): R9 + sE-overlap-by-w1 + w0-only-poll + 128B flag stride. BEST.
// R13 (652us): dual autonomous streams -> 2x MFMA, no chain shortening.
// R14 (826us): chunk streaming -> 16 SEQUENTIAL poll RTs. Lesson: one
//   wave-parallel poll shot, never serialize protocol loads.
// R15 (786us): flags compacted to ONE line -> same-line post/poll convoy at
//   the memory controller. Layout verdict: 128B stride >= 32B >> 4B.
// R16 = R12 verbatim + two changes aimed at the measured ~1.5us/exchange
//   store->observable visibility lag (poll RT ~0.4 + gather ~0.5 don't
//   explain 2.5us/exchange):
//   (1) posts via fire-and-forget global_atomic_swap (no return): atomics
//       execute at the memory-side point immediately (R11 fact) -> flag is
//       observable as soon as issued+drained; cost ~64B/post x 41k = 2.6MB.
//   (2) s_sleep(1) backoff in the poll loop: trims MALL spin queueing at
//       ~27ns detection granularity cost.

typedef __attribute__((ext_vector_type(8))) short short8;
typedef __attribute__((ext_vector_type(4))) float f32x4;

#define MFMA16(a,b,c) __builtin_amdgcn_mfma_f32_16x16x32_bf16(a,b,c,0,0,0)
#define LOAD_RLX(p)    __hip_atomic_load((p), __ATOMIC_RELAXED, __HIP_MEMORY_SCOPE_AGENT)
#define ADD_RLX(p,v)   __hip_atomic_fetch_add((p), (v), __ATOMIC_RELAXED, __HIP_MEMORY_SCOPE_AGENT)

__device__ __forceinline__ short f2bf(float v){
  unsigned u = __float_as_uint(v);
  u = (u + 0x7fffu + ((u >> 16) & 1u)) >> 16;   // RNE to bf16
  return (short)u;
}
__device__ __forceinline__ float bf2f(short s){
  return __uint_as_float(((unsigned)(unsigned short)s) << 16);
}
__device__ __forceinline__ float fast_tanh(float x){
  x = fminf(15.f, fmaxf(-15.f, x));
  float e = __expf(2.f * x);
  return (e - 1.f) * __builtin_amdgcn_rcpf(e + 1.f);
}

__launch_bounds__(128, 1)
__global__ void rnn_kernel(const int* __restrict__ tokens,
                           const float* __restrict__ emb,
                           const float* __restrict__ k0,
                           const float* __restrict__ rk0,
                           const float* __restrict__ b0,
                           const float* __restrict__ k1,
                           const float* __restrict__ rk1,
                           const float* __restrict__ b1,
                           const float* __restrict__ wd,
                           const float* __restrict__ bd,
                           float* __restrict__ out,
                           char* __restrict__ ws)
{
  constexpr int T = 80, E = 100, U = 512;
  const int tid  = threadIdx.x;
  const int w    = tid >> 6;          // wave id (0/1)
  const int lane = tid & 63;
  const int m    = lane & 15;         // row (A) / col (B,C)
  const int q    = lane >> 4;         // quad 0..3

  __shared__ __align__(16) short sW[6][16][520];   // rk0 hi/lo, rk1 hi/lo, k1 hi/lo : [col][k]
  __shared__ __align__(16) short sH[2][16][520];   // h / h0 staging hi,lo : [row][k]
  __shared__ __align__(16) short sE[2][16][136];   // emb rows hi,lo (K padded to 128 w/ zeros)
  __shared__ __align__(16) short sK0[2][16][136];  // k0 slice hi,lo : [col][k] (padded)
  __shared__ int   sTok[16][80];
  __shared__ float sB0[16], sB1[16];
  __shared__ float sRed[16][8];
  __shared__ int   sReg[2];

  // ws layout: regCnt@512 (MALL), flags@4096 (256 x 128B stride -- R12/R15
  // verdict: 128B parallel lines optimal), exchange data @ 40960.
  int*      regCnt = (int*)(ws + 512);             // 8 registration counters, 64B stride
  int*      flags  = (int*)(ws + 4096);            // [cl*32+mem] round-id flags, 128B stride
  unsigned* hPk    = (unsigned*)(ws + 40960);      // h1 packed (hi<<16|lo), [128][512]
  unsigned* h0Pk   = hPk + 128*U;                  // h0 packed

  // -------- dynamic cluster formation: cluster id = physical XCD --------
  int xcc;
  asm volatile("s_getreg_b32 %0, hwreg(HW_REG_XCC_ID)" : "=s"(xcc));
  if (tid == 0){
    int slot = ADD_RLX(regCnt + (xcc & 7)*16, 1);  // 0..31 within this XCD
    sReg[0] = xcc & 7;
    sReg[1] = slot;
  }
  __syncthreads();
  const int cl  = sReg[0];
  const int mem = sReg[1];
  int* const myFlag   = flags + (cl*32 + mem)*32;         // 128B stride
  int* const pollAddr = flags + (cl*32 + (lane & 31))*32; // lane -> member flag

  // ---------------- prologue: stationary weights -> LDS ----------------
  const float* mats[3] = { rk0, rk1, k1 };
  for (int mi = 0; mi < 3; ++mi){
    const float* G = mats[mi];
    for (int i = tid; i < 16*U; i += 128){
      int k = i >> 4, c = i & 15;
      float v  = G[k*U + mem*16 + c];
      short hi = f2bf(v);
      short lo = f2bf(v - bf2f(hi));
      sW[2*mi+0][c][k] = hi;
      sW[2*mi+1][c][k] = lo;
    }
  }
  for (int i = tid; i < 2*16*136; i += 128){ ((short*)sE)[i] = 0; ((short*)sK0)[i] = 0; }
  __syncthreads();
  for (int i = tid; i < 16*E; i += 128){
    int e = i >> 4, c = i & 15;
    float v  = k0[e*U + mem*16 + c];
    short hi = f2bf(v);
    short lo = f2bf(v - bf2f(hi));
    sK0[0][c][e] = hi; sK0[1][c][e] = lo;
  }
  for (int i = tid; i < 16*T; i += 128){
    int r = i / T, t = i - r*T;
    sTok[r][t] = tokens[(cl*16 + r)*T + t];
  }
  if (tid < 16){ sB0[tid] = b0[mem*16 + tid]; sB1[tid] = b1[mem*16 + tid]; }
  __syncthreads();

  // post: drain data stores (vmcnt ack), then lane0 fires an atomic swap of
  // the round id into this member's flag. Atomics execute at the memory-side
  // point immediately (R11 fact) -> no store-buffer visibility lag.
  auto post = [&](int val){
    asm volatile("s_waitcnt vmcnt(0)" ::: "memory");
    if (lane == 0)
      asm volatile("global_atomic_swap %0, %1, off" :: "v"(myFlag), "v"(val) : "memory");
  };
  // wave-parallel poll (WAVE0 ONLY; following barrier releases w1), with
  // s_sleep backoff to trim MALL spin queueing.
  auto pollFlags = [&](int target){
    while (__any(LOAD_RLX(pollAddr) < target)) __builtin_amdgcn_s_sleep(1);
  };
  // gather: 16x dwordx4 sc0, then unpack into sH hi/lo.
  auto gather = [&](const unsigned* srcPk){
    const uint4* s = (const uint4*)(srcPk + cl*16*U);   // 2048 uint4 = 32 KB
    uint4 r[16];
    #pragma unroll
    for (int j = 0; j < 16; ++j)
      asm volatile("global_load_dwordx4 %0, %1, off sc0"
                   : "=v"(r[j]) : "v"(&s[j*128 + tid]));
    asm volatile("s_waitcnt vmcnt(0)" ::: "memory");
    #pragma unroll
    for (int j = 0; j < 16; ++j){
      int i = j*128 + tid, row = i >> 7, c = (i & 127) * 4;
      unsigned h0 = (r[j].x >> 16)     | (r[j].y & 0xffff0000u);
      unsigned h1 = (r[j].z >> 16)     | (r[j].w & 0xffff0000u);
      unsigned l0 = (r[j].x & 0xffffu) | (r[j].y << 16);
      unsigned l1 = (r[j].z & 0xffffu) | (r[j].w << 16);
      uint2 hh; hh.x = h0; hh.y = h1;
      uint2 ll; ll.x = l0; ll.y = l1;
      *(uint2*)&sH[0][row][c] = hh;
      *(uint2*)&sH[1][row][c] = ll;
    }
  };

  const f32x4 zero4 = {0.f, 0.f, 0.f, 0.f};

  // ---------------- recurrence ----------------
  for (int t = 0; t < T; ++t){
    // wave1 stages sE[t] OFF the critical path while wave0 polls.
    // Safe: wave0's last sE[t-1] read retired before the round-B barriers
    // of t-1 (which wave1 passed to get here); wave1 never reads sE.
    if (w == 1){
      float ev[25];
      #pragma unroll
      for (int p = 0; p < 25; ++p){
        int i = lane + p*64;                 // 25*64 = 1600 = 16*E exactly
        ev[p] = emb[sTok[i/E][t]*E + (i % E)];
      }
      #pragma unroll
      for (int p = 0; p < 25; ++p){
        int i = lane + p*64;
        int row = i / E, e = i % E;
        short hi = f2bf(ev[p]);
        short lo = f2bf(ev[p] - bf2f(hi));
        sE[0][row][e] = hi; sE[1][row][e] = lo;
      }
    } else {
      if (t > 0) pollFlags(2*t);             // all round-B(t-1) posts
    }
    __syncthreads();
    if (t > 0) gather(hPk);
    __syncthreads();

    // ---- round A: wave0: h0 = tanh(x@k0 + h@rk0 + b0); wave1: h@rk1 partial
    f32x4 z1a = zero4, z1b = zero4, z1c = zero4, z1d = zero4;
    if (w == 0){
      f32x4 za = zero4, zb = zero4, zc = zero4, zd = zero4;
      #pragma unroll
      for (int kk = 0; kk < 4; ++kk){
        short8 ah = *(const short8*)&sE[0][m][kk*32 + q*8];
        short8 al = *(const short8*)&sE[1][m][kk*32 + q*8];
        short8 bh = *(const short8*)&sK0[0][m][kk*32 + q*8];
        short8 bl = *(const short8*)&sK0[1][m][kk*32 + q*8];
        za = MFMA16(ah, bh, za); zb = MFMA16(al, bh, zb);
        zc = MFMA16(ah, bl, zc); zd = MFMA16(al, bl, zd);
      }
      if (t > 0){
        #pragma unroll
        for (int kk = 0; kk < 16; ++kk){
          short8 ah = *(const short8*)&sH[0][m][kk*32 + q*8];
          short8 al = *(const short8*)&sH[1][m][kk*32 + q*8];
          short8 bh = *(const short8*)&sW[0][m][kk*32 + q*8];
          short8 bl = *(const short8*)&sW[1][m][kk*32 + q*8];
          za = MFMA16(ah, bh, za); zb = MFMA16(al, bh, zb);
          zc = MFMA16(ah, bl, zc); zd = MFMA16(al, bl, zd);
        }
      }
      f32x4 z = za; z += zb; z += zc; z += zd;
      #pragma unroll
      for (int r = 0; r < 4; ++r){
        float h0v = fast_tanh(z[r] + sB0[m]);
        short hi = f2bf(h0v);
        short lo = f2bf(h0v - bf2f(hi));
        int gr = cl*16 + q*4 + r, gc = mem*16 + m;
        unsigned pk = ((unsigned)(unsigned short)hi << 16) | (unsigned short)lo;
        h0Pk[gr*U + gc] = pk;              // plain store (data path)
      }
      post(2*t + 1);                       // h0 ready (this member)
    } else {
      if (t > 0){
        #pragma unroll
        for (int kk = 0; kk < 16; ++kk){
          short8 ah = *(const short8*)&sH[0][m][kk*32 + q*8];
          short8 al = *(const short8*)&sH[1][m][kk*32 + q*8];
          short8 bh = *(const short8*)&sW[2][m][kk*32 + q*8];
          short8 bl = *(const short8*)&sW[3][m][kk*32 + q*8];
          z1a = MFMA16(ah, bh, z1a); z1b = MFMA16(al, bh, z1b);
          z1c = MFMA16(ah, bl, z1c); z1d = MFMA16(al, bl, z1d);
        }
      }
    }

    // ---- round B: h1 = tanh(h0@k1 + h@rk1 + b1)
    if (w == 0) pollFlags(2*t + 1);        // all round-A posts (w1 finishing z1)
    __syncthreads();                       // releases w1; round-A sH reads retired
    gather(h0Pk);
    __syncthreads();
    if (w == 1){
      f32x4 za = zero4, zb = zero4, zc = zero4, zd = zero4;
      #pragma unroll
      for (int kk = 0; kk < 16; ++kk){
        short8 ah = *(const short8*)&sH[0][m][kk*32 + q*8];
        short8 al = *(const short8*)&sH[1][m][kk*32 + q*8];
        short8 bh = *(const short8*)&sW[4][m][kk*32 + q*8];
        short8 bl = *(const short8*)&sW[5][m][kk*32 + q*8];
        za = MFMA16(ah, bh, za); zb = MFMA16(al, bh, zb);
        zc = MFMA16(ah, bl, zc); zd = MFMA16(al, bl, zd);
      }
      f32x4 z = za; z += zb; z += zc; z += zd;
      z += z1a; z += z1b; z += z1c; z += z1d;
      #pragma unroll
      for (int r = 0; r < 4; ++r){
        float h1v = fast_tanh(z[r] + sB1[m]);
        short hi = f2bf(h1v);
        short lo = f2bf(h1v - bf2f(hi));
        int gr = cl*16 + q*4 + r, gc = mem*16 + m;
        unsigned pk = ((unsigned)(unsigned short)hi << 16) | (unsigned short)lo;
        hPk[gr*U + gc] = pk;               // plain store (data path)
      }
      post(2*t + 2);                       // h1 = h(t) ready (this member)
    }
    // no trailing barrier: loop-top poll+barrier aligns waves
  }

  // ---------------- epilogue: logits = h@wd + bd ; sigmoid ----------------
  if (mem == 0){
    if (w == 0) pollFlags(2*T);
    __syncthreads();
    gather(hPk);
    __syncthreads();
    {
      int row = tid >> 3, seg = tid & 7;
      float acc = 0.f;
      for (int u = seg*64; u < seg*64 + 64; ++u){
        float hv = bf2f(sH[0][row][u]) + bf2f(sH[1][row][u]);
        acc += hv * wd[u];
      }
      sRed[row][seg] = acc;
    }
    __syncthreads();
    if (tid < 16){
      float s = bd[0];
      #pragma unroll
      for (int j = 0; j < 8; ++j) s += sRed[tid][j];
      out[cl*16 + tid] = 1.f / (1.f + __expf(-s));
    }
  }

  // replay hygiene (one-time cost)
  __threadfence();
}

extern "C" void kernel_launch(void* const* d_in, const int* in_sizes, int n_in,
                              void* d_out, int out_size, void* d_ws, size_t ws_size,
                              hipStream_t stream) {
  const int*   tokens = (const int*)  d_in[0];
  const float* emb    = (const float*)d_in[1];
  const float* k0     = (const float*)d_in[2];
  const float* rk0    = (const float*)d_in[3];
  const float* b0     = (const float*)d_in[4];
  const float* k1     = (const float*)d_in[5];
  const float* rk1    = (const float*)d_in[6];
  const float* b1     = (const float*)d_in[7];
  const float* wd     = (const float*)d_in[8];
  const float* bd     = (const float*)d_in[9];

  // Zero registration counters + flag region (0xAA poison breaks monotonic
  // arith). regCnt@512, flags@4096..36864; exchange data starts at 40960
  // (fully rewritten at t=0 before first gather — no memset needed there).
  hipMemsetAsync(d_ws, 0, 40960, stream);

  hipLaunchKernelGGL(rnn_kernel, dim3(256), dim3(128), 0, stream,
                     tokens, emb, k0, rk0, b0, k1, rk1, b1, wd, bd,
                     (float*)d_out, (char*)d_ws);
}